// Round 6
// baseline (38.416 us; speedup 1.0000x reference)
//
#include <hip/hip_runtime.h>
#include <hip/hip_bf16.h>
#include <stdint.h>

// pooled[b,i,:] = bias + sum_{j!=i} W_cell(b,i,j) . hid[b,j,:]
// R6: barrier-free main loop. Block = 4 waves (256 thr), wave w owns ho slice
// [w*32, w*32+32). Per cell (NO __syncthreads):
//   stage-1: z(all 64 j, 32 ho) = hid @ W_c^T       (32 MFMA; A=hid hoisted regs,
//                                                    B=W streamed from L2, prefetched)
//   z -> wave-PRIVATE 4KB LDS scratch (XOR-swizzled, lgkmcnt-ordered only)
//   stage-2: acc(64 i, 32 ho) += mask @ z           (16 MFMA; mask built in regs
//                                                    from hoisted cellt bytes)
// Sync only in init (cellt/Hs). Partials over 8 chunks + reduce.

typedef __attribute__((ext_vector_type(8))) short bf16x8;
typedef __attribute__((ext_vector_type(4))) float f32x4;
typedef unsigned int u32;

#define NCHUNK 8   // cell chunks -> 64*NCHUNK = 512 blocks
#define CPB 8      // cells per block

__device__ inline unsigned short bf16bits(float x) {
    __hip_bfloat16 h = __float2bfloat16(x);
    return *reinterpret_cast<unsigned short*>(&h);
}

// ---- P1: W f32 [128][8192] -> Wb bf16 [c=64][hg=16][ho=128][e=8] ----
__global__ __launch_bounds__(512)
void gp_wconv(const float* __restrict__ W, __hip_bfloat16* __restrict__ Wb)
{
    __shared__ __attribute__((aligned(16))) __hip_bfloat16 Wl[128][136];
    const int c = blockIdx.x, t = threadIdx.x;
    #pragma unroll
    for (int q = 0; q < 8; ++q) {
        int flat = q * 512 + t;
        int ho = flat >> 5, k4 = flat & 31;
        float4 v = *(const float4*)(W + (size_t)ho * 8192 + c * 128 + k4 * 4);
        __hip_bfloat16* d = &Wl[ho][k4 * 4];
        d[0] = __float2bfloat16(v.x); d[1] = __float2bfloat16(v.y);
        d[2] = __float2bfloat16(v.z); d[3] = __float2bfloat16(v.w);
    }
    __syncthreads();
    #pragma unroll
    for (int q = 0; q < 4; ++q) {
        int flat = q * 512 + t;            // flat = hg*128 + ho
        int hg = flat >> 7, ho = flat & 127;
        bf16x8 v = *(const bf16x8*)&Wl[ho][hg * 8];
        *(bf16x8*)(Wb + (size_t)c * 16384 + (size_t)flat * 8) = v;
    }
}

// ---- main: grid = NCHUNK*64, block = 256 (4 waves) ----
__global__ __launch_bounds__(256, 2)
void gp_main(const float* __restrict__ hid, const float* __restrict__ pos,
             const __hip_bfloat16* __restrict__ Wb, float* __restrict__ partial)
{
    __shared__ __attribute__((aligned(16))) __hip_bfloat16 Hs[16 * 64 * 8]; // [hg][j][e] 16KB
    __shared__ u32 zscr[4][1024];              // per-wave [jp 32][hol 32] u32, swizzled; 16KB
    __shared__ unsigned char cellt[64 * 64];   // [i][j] 4KB
    __shared__ float ps[128];

    const int t = threadIdx.x;
    const int b = blockIdx.x & 63, chunk = blockIdx.x >> 6;
    const int w = t >> 6, lane = t & 63;
    const int l15 = lane & 15, kg = lane >> 4;

    if (t < 128) ps[t] = pos[(size_t)b * 128 + t];
    __syncthreads();

    // cell table (trunc-toward-zero, clip, gx-major; self = 255)
    #pragma unroll
    for (int q = 0; q < 16; ++q) {
        int idx = q * 256 + t;
        int i = idx >> 6, j = idx & 63;
        float rx = ps[j * 2 + 0] - ps[i * 2 + 0];
        float ry = ps[j * 2 + 1] - ps[i * 2 + 1];
        int gx = (int)((rx + 2.0f) * 2.0f);
        int gy = (int)((ry + 2.0f) * 2.0f);
        gx = gx < 0 ? 0 : (gx > 7 ? 7 : gx);
        gy = gy < 0 ? 0 : (gy > 7 ? 7 : gy);
        cellt[idx] = (i == j) ? 255 : (unsigned char)(gx * 8 + gy);
    }
    // stage hid[b] -> Hs [hg][j][e]
    #pragma unroll
    for (int q = 0; q < 4; ++q) {
        int idx = q * 256 + t;
        int hg = idx >> 6, j = idx & 63;
        const float* src = hid + ((size_t)b * 64 + j) * 128 + hg * 8;
        float4 v0 = *(const float4*)src;
        float4 v1 = *(const float4*)(src + 4);
        __hip_bfloat16* d = &Hs[(hg * 64 + j) * 8];
        d[0] = __float2bfloat16(v0.x); d[1] = __float2bfloat16(v0.y);
        d[2] = __float2bfloat16(v0.z); d[3] = __float2bfloat16(v0.w);
        d[4] = __float2bfloat16(v1.x); d[5] = __float2bfloat16(v1.y);
        d[6] = __float2bfloat16(v1.z); d[7] = __float2bfloat16(v1.w);
    }
    __syncthreads();   // <-- the ONLY barrier before the epilogue

    // hoist hid A-frags: a[jt][ks] (all 64 j, 16 frags = 64 VGPR)
    bf16x8 a[4][4];
    #pragma unroll
    for (int jt = 0; jt < 4; ++jt)
        #pragma unroll
        for (int ks = 0; ks < 4; ++ks) {
            int hg = ks * 4 + kg;
            a[jt][ks] = *(const bf16x8*)&Hs[(hg * 64 + jt * 16 + l15) * 8];
        }
    // hoist cellt bytes for stage-2 mask frags: cs[mt][ks2] = 8 bytes
    uint2 cs[4][2];
    #pragma unroll
    for (int mt = 0; mt < 4; ++mt)
        #pragma unroll
        for (int ks2 = 0; ks2 < 2; ++ks2)
            cs[mt][ks2] = *(const uint2*)&cellt[(mt * 16 + l15) * 64 + ks2 * 32 + kg * 8];

    f32x4 acc[4][2];
    #pragma unroll
    for (int mt = 0; mt < 4; ++mt) {
        acc[mt][0] = (f32x4){0.f, 0.f, 0.f, 0.f};
        acc[mt][1] = (f32x4){0.f, 0.f, 0.f, 0.f};
    }

    u32* zw = &zscr[w][0];

    // preload W frags for first cell: wf[parity][ks][fh]
    bf16x8 wf[2][4][2];
    {
        const __hip_bfloat16* wc = Wb + (size_t)(chunk * CPB) * 16384;
        #pragma unroll
        for (int ks = 0; ks < 4; ++ks)
            #pragma unroll
            for (int fh = 0; fh < 2; ++fh)
                wf[0][ks][fh] = *(const bf16x8*)(wc +
                    ((size_t)(ks * 4 + kg) * 128 + w * 32 + fh * 16 + l15) * 8);
    }

    #pragma unroll
    for (int cc = 0; cc < CPB; ++cc) {
        const int p = cc & 1;
        const int c = chunk * CPB + cc;

        // prefetch next cell's W frags (registers; compiler tracks vmcnt per-reg)
        if (cc + 1 < CPB) {
            const __hip_bfloat16* wc = Wb + (size_t)(c + 1) * 16384;
            #pragma unroll
            for (int ks = 0; ks < 4; ++ks)
                #pragma unroll
                for (int fh = 0; fh < 2; ++fh)
                    wf[p ^ 1][ks][fh] = *(const bf16x8*)(wc +
                        ((size_t)(ks * 4 + kg) * 128 + w * 32 + fh * 16 + l15) * 8);
        }

        // stage-1: z[jt][fh] = hid(j x h) @ W_c^T(h x ho), 32 MFMA
        f32x4 z[4][2];
        #pragma unroll
        for (int jt = 0; jt < 4; ++jt) {
            z[jt][0] = (f32x4){0.f, 0.f, 0.f, 0.f};
            z[jt][1] = (f32x4){0.f, 0.f, 0.f, 0.f};
        }
        #pragma unroll
        for (int ks = 0; ks < 4; ++ks)
            #pragma unroll
            for (int jt = 0; jt < 4; ++jt) {
                z[jt][0] = __builtin_amdgcn_mfma_f32_16x16x32_bf16(a[jt][ks], wf[p][ks][0], z[jt][0], 0, 0, 0);
                z[jt][1] = __builtin_amdgcn_mfma_f32_16x16x32_bf16(a[jt][ks], wf[p][ks][1], z[jt][1], 0, 0, 0);
            }

        // pack z -> wave-private zscr (u32 = bf16 pair (j even, j odd))
        // D: col=l15=ho, row j = jt*16 + kg*4 + r.  jp = j/2 = jt*8 + kg*2 + q.
        // swizzle: addr32 = (jp*32 + hol) ^ (((jp>>2)&3)<<3)
        #pragma unroll
        for (int jt = 0; jt < 4; ++jt)
            #pragma unroll
            for (int fh = 0; fh < 2; ++fh) {
                u32 p0 = (u32)bf16bits(z[jt][fh][0]) | ((u32)bf16bits(z[jt][fh][1]) << 16);
                u32 p1 = (u32)bf16bits(z[jt][fh][2]) | ((u32)bf16bits(z[jt][fh][3]) << 16);
                int X = ((jt * 2 + (kg >> 1)) & 3) << 3;
                int a32 = (((jt * 8 + kg * 2) * 32) + fh * 16 + l15) ^ X;
                zw[a32] = p0;        // jp = jt*8+kg*2   (q=0)
                zw[a32 + 32] = p1;   // jp+1             (q=1), same X
            }

        // read B2 frags (k=j): lane(l15,kg) word u <- jp = ks2*16+kg*4+u
        bf16x8 b2[2][2];
        #pragma unroll
        for (int ks2 = 0; ks2 < 2; ++ks2)
            #pragma unroll
            for (int fh = 0; fh < 2; ++fh) {
                int base = (((ks2 * 16 + kg * 4) * 32) + fh * 16 + l15) ^ (kg << 3);
                union { u32 wd[4]; bf16x8 v; } r;
                r.wd[0] = zw[base];
                r.wd[1] = zw[base + 32];
                r.wd[2] = zw[base + 64];
                r.wd[3] = zw[base + 96];
                b2[ks2][fh] = r.v;
            }

        // stage-2: acc(i,ho) += mask(i x j) @ z(j x ho); mask frags built in regs
        #pragma unroll
        for (int mt = 0; mt < 4; ++mt) {
            #pragma unroll
            for (int ks2 = 0; ks2 < 2; ++ks2) {
                union { u32 wd[4]; bf16x8 v; } m;
                u32 s0 = cs[mt][ks2].x, s1 = cs[mt][ks2].y;
                #pragma unroll
                for (int k = 0; k < 4; ++k) {
                    u32 s = (k < 2) ? s0 : s1;
                    u32 b0 = (s >> ((k & 1) * 16)) & 0xFFu;
                    u32 b1 = (s >> ((k & 1) * 16 + 8)) & 0xFFu;
                    m.wd[k] = (b0 == (u32)c ? 0x3F80u : 0u) | (b1 == (u32)c ? 0x3F800000u : 0u);
                }
                acc[mt][0] = __builtin_amdgcn_mfma_f32_16x16x32_bf16(m.v, b2[ks2][0], acc[mt][0], 0, 0, 0);
                acc[mt][1] = __builtin_amdgcn_mfma_f32_16x16x32_bf16(m.v, b2[ks2][1], acc[mt][1], 0, 0, 0);
            }
        }
    }

    // epilogue: partial[chunk][b][i][ho]
    float* pb = partial + (((size_t)chunk * 64 + b) * 64) * 128;
    #pragma unroll
    for (int mt = 0; mt < 4; ++mt)
        #pragma unroll
        for (int fh = 0; fh < 2; ++fh)
            #pragma unroll
            for (int r = 0; r < 4; ++r) {
                int i = mt * 16 + kg * 4 + r;
                int ho = w * 32 + fh * 16 + l15;
                pb[(size_t)i * 128 + ho] = acc[mt][fh][r];
            }
}

// ---- reduce: out = bias + sum_chunk partial ----
__global__ __launch_bounds__(512)
void gp_reduce(const float* __restrict__ partial, const float* __restrict__ bias,
               float* __restrict__ out)
{
    int gid = blockIdx.x * 512 + threadIdx.x;  // 131072 float4s
    int ho4 = gid & 31;
    float4 a = *(const float4*)(bias + ho4 * 4);
    #pragma unroll
    for (int ch = 0; ch < NCHUNK; ++ch) {
        float4 v = *(const float4*)(partial + (size_t)ch * 524288 + (size_t)gid * 4);
        a.x += v.x; a.y += v.y; a.z += v.z; a.w += v.w;
    }
    *(float4*)(out + (size_t)gid * 4) = a;
}

extern "C" void kernel_launch(void* const* d_in, const int* in_sizes, int n_in,
                              void* d_out, int out_size, void* d_ws, size_t ws_size,
                              hipStream_t stream)
{
    const float* hid  = (const float*)d_in[0];  // [64,64,128]
    const float* pos  = (const float*)d_in[1];  // [64,64,2]
    const float* W    = (const float*)d_in[2];  // [128,8192]
    const float* bias = (const float*)d_in[3];  // [128]
    float* out = (float*)d_out;

    __hip_bfloat16* Wb = (__hip_bfloat16*)d_ws;                 // 2 MB
    float* partial = (float*)((char*)d_ws + (size_t)2097152);   // 16 MB

    hipLaunchKernelGGL(gp_wconv,  dim3(64),          dim3(512), 0, stream, W, Wb);
    hipLaunchKernelGGL(gp_main,   dim3(NCHUNK * 64), dim3(256), 0, stream, hid, pos, Wb, partial);
    hipLaunchKernelGGL(gp_reduce, dim3(256),         dim3(512), 0, stream, partial, bias, out);
}